// Round 1
// baseline (273.081 us; speedup 1.0000x reference)
//
#include <hip/hip_runtime.h>
#include <stdint.h>

#define DD 1024
#define MROWS 32768

typedef __attribute__((ext_vector_type(8))) short short8;
typedef __attribute__((ext_vector_type(8))) unsigned short ushort8;
typedef __attribute__((ext_vector_type(4))) float f32x4;

static __device__ __forceinline__ unsigned short f2bf(float f) {
    union { float f; uint32_t u; } c;
    c.f = f;
    uint32_t u = c.u;
    u += 0x7FFFu + ((u >> 16) & 1u);   // round-to-nearest-even
    return (unsigned short)(u >> 16);
}

static __device__ __forceinline__ void gload_lds16(const void* g, void* l) {
    __builtin_amdgcn_global_load_lds(
        (const __attribute__((address_space(1))) uint32_t*)g,
        (__attribute__((address_space(3))) uint32_t*)l,
        16, 0, 0);
}

// Reconstruct w = th*sign*(th>0), cast to bf16, store TRANSPOSED: wT[n][k] = w[k][n].
// 64x64 tiles via LDS; blockIdx.z selects layer.
__global__ __launch_bounds__(256) void build_wT_kernel(
        const float* __restrict__ th1, const float* __restrict__ sg1,
        const float* __restrict__ th2, const float* __restrict__ sg2,
        unsigned short* __restrict__ wT1, unsigned short* __restrict__ wT2) {
    __shared__ unsigned short tile[64][65];
    const float* th = blockIdx.z ? th2 : th1;
    const float* sg = blockIdx.z ? sg2 : sg1;
    unsigned short* wT = blockIdx.z ? wT2 : wT1;
    const int bk = blockIdx.x;  // k-tile index
    const int bn = blockIdx.y;  // n-tile index
    const int t = threadIdx.x;
    #pragma unroll
    for (int i = 0; i < 4; ++i) {
        int idx = i * 256 + t;
        int r  = idx >> 4;   // k within tile (0..63)
        int cg = idx & 15;   // 4-col group (n)
        size_t base = (size_t)(bk * 64 + r) * DD + bn * 64 + cg * 4;
        const float4 tv = *(const float4*)&th[base];
        const float4 sv = *(const float4*)&sg[base];
        tile[r][cg * 4 + 0] = f2bf(tv.x > 0.f ? tv.x * sv.x : 0.f);
        tile[r][cg * 4 + 1] = f2bf(tv.y > 0.f ? tv.y * sv.y : 0.f);
        tile[r][cg * 4 + 2] = f2bf(tv.z > 0.f ? tv.z * sv.z : 0.f);
        tile[r][cg * 4 + 3] = f2bf(tv.w > 0.f ? tv.w * sv.w : 0.f);
    }
    __syncthreads();
    #pragma unroll
    for (int i = 0; i < 4; ++i) {
        int idx = i * 256 + t;
        int nr = idx >> 4;   // n within tile (0..63)
        int kg = idx & 15;   // 4-k group
        uint32_t lo = tile[kg * 4 + 0][nr] | ((uint32_t)tile[kg * 4 + 1][nr] << 16);
        uint32_t hi = tile[kg * 4 + 2][nr] | ((uint32_t)tile[kg * 4 + 3][nr] << 16);
        *(uint2*)&wT[(size_t)(bn * 64 + nr) * DD + bk * 64 + kg * 4] = make_uint2(lo, hi);
    }
}

// C[m][n] = act(A[m][:] . B^T[n][:]) — m97-structure 128x128 tile, BK=32,
// 4 waves of 64x64, v_mfma_f32_16x16x32_bf16.
// A_FP32: A is fp32, reg-staged with fp32->bf16 convert. Else bf16 via global_load_lds.
// STORE_BF16: ReLU + bf16 store (intermediate Y1); else ReLU + fp32 store.
template<bool A_FP32, bool STORE_BF16>
__global__ __launch_bounds__(256) void gemm_bt(
        const void* __restrict__ Ap,
        const unsigned short* __restrict__ Bt,   // [1024 n][1024 k] bf16
        void* __restrict__ Cp) {
    __shared__ unsigned short sA[128 * 32];   // [row m][k] bf16
    __shared__ unsigned short sB[128 * 32];   // [row n][k] bf16

    const int tid  = threadIdx.x;
    const int lane = tid & 63;
    const int wid  = tid >> 6;       // 0..3
    const int bm   = blockIdx.x >> 3;
    const int bn   = blockIdx.x & 7;
    const int wm   = wid >> 1;       // 0..1
    const int wn   = wid & 1;        // 0..1

    const f32x4 vzero = {0.f, 0.f, 0.f, 0.f};
    f32x4 acc[4][4];
    #pragma unroll
    for (int i = 0; i < 4; ++i)
        #pragma unroll
        for (int j = 0; j < 4; ++j) acc[i][j] = vzero;

    // global_load_lds staging addresses (wave-uniform LDS base + lane*16B)
    const int l4r = lane >> 2;       // row within 16-row chunk
    const int l4c = lane & 3;        // 8-elem k group
    const unsigned short* bsrc =
        &Bt[(size_t)(bn * 128 + wid * 32 + l4r) * DD + l4c * 8];
    const unsigned short* asrcb = nullptr;
    const float* af32 = nullptr;
    if (A_FP32) {
        af32 = (const float*)Ap;
    } else {
        asrcb = &((const unsigned short*)Ap)[(size_t)(bm * 128 + wid * 32 + l4r) * DD + l4c * 8];
    }

    // fragment read bases
    const int fr = lane & 15, fq = lane >> 4;
    const unsigned short* sAr = &sA[(wm * 64 + fr) * 32 + fq * 8];
    const unsigned short* sBr = &sB[(wn * 64 + fr) * 32 + fq * 8];

    for (int k0 = 0; k0 < DD; k0 += 32) {
        // ---- stage B (and A) tiles ----
        gload_lds16(bsrc + k0,            &sB[(wid * 32) * 32]);
        gload_lds16(bsrc + 16 * DD + k0,  &sB[(wid * 32 + 16) * 32]);
        if (A_FP32) {
            #pragma unroll
            for (int i = 0; i < 2; ++i) {
                int idx = i * 256 + tid;
                int row = idx >> 2;      // 0..127
                int cg  = idx & 3;       // 8-col group
                const float4* p = (const float4*)&af32[(size_t)(bm * 128 + row) * DD + k0 + cg * 8];
                float4 v0 = p[0], v1 = p[1];
                ushort8 w;
                w[0] = f2bf(v0.x); w[1] = f2bf(v0.y); w[2] = f2bf(v0.z); w[3] = f2bf(v0.w);
                w[4] = f2bf(v1.x); w[5] = f2bf(v1.y); w[6] = f2bf(v1.z); w[7] = f2bf(v1.w);
                *(ushort8*)&sA[row * 32 + cg * 8] = w;
            }
        } else {
            gload_lds16(asrcb + k0,           &sA[(wid * 32) * 32]);
            gload_lds16(asrcb + 16 * DD + k0, &sA[(wid * 32 + 16) * 32]);
        }
        __syncthreads();

        // ---- fragments + 16 MFMA ----
        short8 av[4], bv[4];
        #pragma unroll
        for (int mi = 0; mi < 4; ++mi) av[mi] = *(const short8*)(sAr + mi * 512);
        #pragma unroll
        for (int ni = 0; ni < 4; ++ni) bv[ni] = *(const short8*)(sBr + ni * 512);
        #pragma unroll
        for (int mi = 0; mi < 4; ++mi)
            #pragma unroll
            for (int ni = 0; ni < 4; ++ni)
                acc[mi][ni] = __builtin_amdgcn_mfma_f32_16x16x32_bf16(
                    av[mi], bv[ni], acc[mi][ni], 0, 0, 0);
        __syncthreads();
    }

    // ---- epilogue: ReLU + store ----
    const int orow0 = bm * 128 + wm * 64 + fq * 4;
    const int ocol0 = bn * 128 + wn * 64 + fr;
    #pragma unroll
    for (int mi = 0; mi < 4; ++mi)
        #pragma unroll
        for (int ni = 0; ni < 4; ++ni)
            #pragma unroll
            for (int r = 0; r < 4; ++r) {
                float v = fmaxf(acc[mi][ni][r], 0.f);
                size_t off = (size_t)(orow0 + mi * 16 + r) * DD + (ocol0 + ni * 16);
                if (STORE_BF16) ((unsigned short*)Cp)[off] = f2bf(v);
                else            ((float*)Cp)[off] = v;
            }
}

// Safety net if d_ws is too small: fused fp32 VALU path, no workspace.
__global__ __launch_bounds__(256) void fallback_fused(
        const float* __restrict__ x,
        const float* __restrict__ th1, const float* __restrict__ sg1,
        const float* __restrict__ th2, const float* __restrict__ sg2,
        float* __restrict__ out) {
    __shared__ float xr[8][DD];
    __shared__ float y1[8][DD];
    const int rb = blockIdx.x * 8;
    const int t = threadIdx.x;
    for (int r = 0; r < 8; ++r)
        for (int i = t; i < DD; i += 256)
            xr[r][i] = x[(size_t)(rb + r) * DD + i];
    __syncthreads();
    for (int jo = 0; jo < 4; ++jo) {
        const int j = jo * 256 + t;
        float a[8] = {0, 0, 0, 0, 0, 0, 0, 0};
        for (int k = 0; k < DD; ++k) {
            float tv = th1[(size_t)k * DD + j];
            float w = tv > 0.f ? tv * sg1[(size_t)k * DD + j] : 0.f;
            #pragma unroll
            for (int r = 0; r < 8; ++r) a[r] += xr[r][k] * w;
        }
        #pragma unroll
        for (int r = 0; r < 8; ++r) y1[r][j] = fmaxf(a[r], 0.f);
    }
    __syncthreads();
    for (int jo = 0; jo < 4; ++jo) {
        const int j = jo * 256 + t;
        float a[8] = {0, 0, 0, 0, 0, 0, 0, 0};
        for (int k = 0; k < DD; ++k) {
            float tv = th2[(size_t)k * DD + j];
            float w = tv > 0.f ? tv * sg2[(size_t)k * DD + j] : 0.f;
            #pragma unroll
            for (int r = 0; r < 8; ++r) a[r] += y1[r][k] * w;
        }
        #pragma unroll
        for (int r = 0; r < 8; ++r) out[(size_t)(rb + r) * DD + j] = fmaxf(a[r], 0.f);
    }
}

extern "C" void kernel_launch(void* const* d_in, const int* in_sizes, int n_in,
                              void* d_out, int out_size, void* d_ws, size_t ws_size,
                              hipStream_t stream) {
    const float* x   = (const float*)d_in[0];
    const float* th1 = (const float*)d_in[1];
    const float* sg1 = (const float*)d_in[2];
    const float* th2 = (const float*)d_in[3];
    const float* sg2 = (const float*)d_in[4];
    float* out = (float*)d_out;

    const size_t need = ((size_t)2 * 1024 * 1024 + (size_t)MROWS * 1024) * 2;  // wT1+wT2+Y1 bf16
    if (ws_size >= need) {
        unsigned short* wT1 = (unsigned short*)d_ws;
        unsigned short* wT2 = wT1 + 1024 * 1024;
        unsigned short* Y1  = wT2 + 1024 * 1024;
        build_wT_kernel<<<dim3(16, 16, 2), 256, 0, stream>>>(th1, sg1, th2, sg2, wT1, wT2);
        gemm_bt<true,  true ><<<dim3((MROWS / 128) * 8), 256, 0, stream>>>(x,  wT1, Y1);
        gemm_bt<false, false><<<dim3((MROWS / 128) * 8), 256, 0, stream>>>(Y1, wT2, out);
    } else {
        fallback_fused<<<MROWS / 8, 256, 0, stream>>>(x, th1, sg1, th2, sg2, out);
    }
}

// Round 2
// 258.444 us; speedup vs baseline: 1.0566x; 1.0566x over previous
//
#include <hip/hip_runtime.h>
#include <stdint.h>

#define DD 1024
#define MROWS 32768
#define NT 16   // K-tiles: 1024 / 64

typedef __attribute__((ext_vector_type(8))) short short8;
typedef __attribute__((ext_vector_type(4))) float f32x4;

static __device__ __forceinline__ unsigned short f2bf(float f) {
    union { float f; uint32_t u; } c;
    c.f = f;
    uint32_t u = c.u;
    u += 0x7FFFu + ((u >> 16) & 1u);   // RNE
    return (unsigned short)(u >> 16);
}

static __device__ __forceinline__ void gload_lds16(const void* g, void* l) {
    __builtin_amdgcn_global_load_lds(
        (const __attribute__((address_space(1))) uint32_t*)g,
        (__attribute__((address_space(3))) uint32_t*)l,
        16, 0, 0);
}

#define SBAR() __builtin_amdgcn_s_barrier()
#define LGKM0() asm volatile("s_waitcnt lgkmcnt(0)" ::: "memory")
#define VMC6()  asm volatile("s_waitcnt vmcnt(6)" ::: "memory")
#define VMC0()  asm volatile("s_waitcnt vmcnt(0)" ::: "memory")

static __device__ __forceinline__ short8 cvt8(f32x4 lo, f32x4 hi) {
    short8 r;
    #pragma unroll
    for (int i = 0; i < 4; ++i) r[i] = (short)f2bf(lo[i]);
    #pragma unroll
    for (int i = 0; i < 4; ++i) r[4 + i] = (short)f2bf(hi[i]);
    return r;
}

// ---------------- weight reconstruction: wT[n][k] = bf16(th*sign*(th>0))[k][n]
__global__ __launch_bounds__(256) void build_wT_kernel(
        const float* __restrict__ th1, const float* __restrict__ sg1,
        const float* __restrict__ th2, const float* __restrict__ sg2,
        unsigned short* __restrict__ wT1, unsigned short* __restrict__ wT2) {
    __shared__ unsigned short tile[64][65];
    const float* th = blockIdx.z ? th2 : th1;
    const float* sg = blockIdx.z ? sg2 : sg1;
    unsigned short* wT = blockIdx.z ? wT2 : wT1;
    const int bk = blockIdx.x, bn = blockIdx.y, t = threadIdx.x;
    #pragma unroll
    for (int i = 0; i < 4; ++i) {
        int idx = i * 256 + t;
        int r = idx >> 4, cg = idx & 15;
        size_t base = (size_t)(bk * 64 + r) * DD + bn * 64 + cg * 4;
        const float4 tv = *(const float4*)&th[base];
        const float4 sv = *(const float4*)&sg[base];
        tile[r][cg * 4 + 0] = f2bf(tv.x > 0.f ? tv.x * sv.x : 0.f);
        tile[r][cg * 4 + 1] = f2bf(tv.y > 0.f ? tv.y * sv.y : 0.f);
        tile[r][cg * 4 + 2] = f2bf(tv.z > 0.f ? tv.z * sv.z : 0.f);
        tile[r][cg * 4 + 3] = f2bf(tv.w > 0.f ? tv.w * sv.w : 0.f);
    }
    __syncthreads();
    #pragma unroll
    for (int i = 0; i < 4; ++i) {
        int idx = i * 256 + t;
        int nr = idx >> 4, kg = idx & 15;
        uint32_t lo = tile[kg * 4 + 0][nr] | ((uint32_t)tile[kg * 4 + 1][nr] << 16);
        uint32_t hi = tile[kg * 4 + 2][nr] | ((uint32_t)tile[kg * 4 + 3][nr] << 16);
        *(uint2*)&wT[(size_t)(bn * 64 + nr) * DD + bk * 64 + kg * 4] = make_uint2(lo, hi);
    }
}

// ---------------- 8-phase GEMM: C = act(A . Bt^T)
// A_FP32=true : A fp32 (x), BM=128, stores bf16 (Y1)
// A_FP32=false: A bf16 (Y1), BM=256, stores fp32 (out)
template<bool A_FP32>
__global__ __launch_bounds__(512, 2) void gemm8p(
        const void* __restrict__ Ap,
        const unsigned short* __restrict__ Bt,   // [1024 n][1024 k] bf16
        void* __restrict__ Cp) {
    constexpr int BM    = A_FP32 ? 128 : 256;
    constexpr int M_REP = A_FP32 ? 4 : 8;
    constexpr int MI_PH = A_FP32 ? 1 : 2;   // mi-frags per phase

    __shared__ unsigned short sB[2][256 * 64];                    // 64 KiB
    __shared__ float          sAf[A_FP32 ? 2 * 128 * 64 : 2];     // 64 KiB | 8 B
    __shared__ unsigned short sAh[A_FP32 ? 2 : 2 * 256 * 64];     // 4 B | 64 KiB

    const int tid = threadIdx.x;
    const int lane = tid & 63, wid = tid >> 6;
    const int wm = wid >> 2, wn = wid & 3;
    const int fr = lane & 15, fq = lane >> 4;

    // T1: XCD-chunked swizzle, bn-minor (A-panel-sharing blocks co-resident)
    constexpr int NBLK = (MROWS / BM) * 4;
    const int s = blockIdx.x;
    const int L = (s & 7) * (NBLK >> 3) + (s >> 3);
    const int bm = L >> 2, bn = L & 3;

    // staging source pointers (pre-swizzled global addresses, T2 write side)
    const int brow = wid * 8 + (lane >> 3);            // row within 64-row chunk
    const int bslot = (lane & 7) ^ (lane >> 3);        // 16B-slot (XOR row&7)
    const unsigned short* bsrc0 = Bt + (size_t)(bn * 256 + brow) * DD + bslot * 8;

    const float* afsrc0 = nullptr;
    const unsigned short* ahsrc0 = nullptr;
    if constexpr (A_FP32) {
        const int arow = wid * 4 + (lane >> 4);        // row within 32-row chunk
        const int aslot = (lane & 15) ^ (arow & 7);
        afsrc0 = (const float*)Ap + (size_t)(bm * 128 + arow) * DD + aslot * 4;
    } else {
        ahsrc0 = (const unsigned short*)Ap + (size_t)(bm * 256 + brow) * DD + bslot * 8;
    }

    auto stageB = [&](int b, int c, int kt) {
        gload_lds16(bsrc0 + (size_t)c * 64 * DD + kt * 64,
                    &sB[b][(c * 64 + wid * 8) * 64]);
    };
    auto stageA = [&](int b, int c, int kt) {
        if constexpr (A_FP32)
            gload_lds16(afsrc0 + (size_t)c * 32 * DD + kt * 64,
                        &sAf[(size_t)(b * 128 + c * 32 + wid * 4) * 64]);
        else
            gload_lds16(ahsrc0 + (size_t)c * 64 * DD + kt * 64,
                        &sAh[(size_t)(b * 256 + c * 64 + wid * 8) * 64]);
    };

    // fragment reads (T2 read side: same XOR)
    auto readB = [&](int b, int ni, int kk) -> short8 {
        int row = wn * 64 + ni * 16 + fr;
        int off = (kk * 64 + fq * 16) ^ ((row & 7) << 4);
        return *(const short8*)((const char*)&sB[b][0] + row * 128 + off);
    };
    auto readA = [&](int b, int mi, int kk) -> short8 {
        if constexpr (A_FP32) {
            int row = wm * 64 + mi * 16 + fr;
            const char* base = (const char*)&sAf[(size_t)b * 128 * 64] + row * 256;
            int s0 = ((kk * 8 + fq * 2 + 0) ^ (row & 7)) << 4;
            int s1 = ((kk * 8 + fq * 2 + 1) ^ (row & 7)) << 4;
            f32x4 lo = *(const f32x4*)(base + s0);
            f32x4 hi = *(const f32x4*)(base + s1);
            return cvt8(lo, hi);
        } else {
            int row = wm * 128 + mi * 16 + fr;
            int off = (kk * 64 + fq * 16) ^ ((row & 7) << 4);
            return *(const short8*)((const char*)&sAh[(size_t)b * 256 * 64] + row * 128 + off);
        }
    };

    const f32x4 vz = {0.f, 0.f, 0.f, 0.f};
    f32x4 acc[M_REP][4];
    #pragma unroll
    for (int i = 0; i < M_REP; ++i)
        #pragma unroll
        for (int j = 0; j < 4; ++j) acc[i][j] = vz;
    short8 bfr[4][2];

    // prologue: tile0 fully, tile1 minus A-chunks 1,3
    #pragma unroll
    for (int c = 0; c < 4; ++c) stageB(0, c, 0);
    #pragma unroll
    for (int c = 0; c < 4; ++c) stageA(0, c, 0);
    #pragma unroll
    for (int c = 0; c < 4; ++c) stageB(1, c, 1);
    stageA(1, 0, 1); stageA(1, 2, 1);
    VMC6(); SBAR();

    for (int kt = 0; kt < NT; ++kt) {
        const int cur = kt & 1;
        const bool pf = (kt + 2 < NT);

        // -------- phase 1: A-quad 0 + all B reads; stage A1,A3 of kt+1 --------
        {
            short8 a[MI_PH][2];
            #pragma unroll
            for (int j = 0; j < MI_PH; ++j)
                #pragma unroll
                for (int kk = 0; kk < 2; ++kk) a[j][kk] = readA(cur, j, kk);
            #pragma unroll
            for (int ni = 0; ni < 4; ++ni)
                #pragma unroll
                for (int kk = 0; kk < 2; ++kk) bfr[ni][kk] = readB(cur, ni, kk);
            if (kt + 1 < NT) { stageA(cur ^ 1, 1, kt + 1); stageA(cur ^ 1, 3, kt + 1); }
            SBAR(); LGKM0();
            __builtin_amdgcn_s_setprio(1);
            #pragma unroll
            for (int j = 0; j < MI_PH; ++j)
                #pragma unroll
                for (int ni = 0; ni < 4; ++ni)
                    #pragma unroll
                    for (int kk = 0; kk < 2; ++kk)
                        acc[j][ni] = __builtin_amdgcn_mfma_f32_16x16x32_bf16(
                            a[j][kk], bfr[ni][kk], acc[j][ni], 0, 0, 0);
            __builtin_amdgcn_s_setprio(0);
            SBAR();
        }
        // -------- phases 2..4 --------
        #pragma unroll
        for (int p = 1; p < 4; ++p) {
            short8 a[MI_PH][2];
            #pragma unroll
            for (int j = 0; j < MI_PH; ++j)
                #pragma unroll
                for (int kk = 0; kk < 2; ++kk) a[j][kk] = readA(cur, MI_PH * p + j, kk);
            if (pf) {
                if (p == 1)      { stageB(cur, 0, kt + 2); stageB(cur, 1, kt + 2); }
                else if (p == 2) { stageB(cur, 2, kt + 2); stageB(cur, 3, kt + 2); }
                else             { stageA(cur, 0, kt + 2); stageA(cur, 2, kt + 2); }
            }
            SBAR(); LGKM0();
            __builtin_amdgcn_s_setprio(1);
            #pragma unroll
            for (int j = 0; j < MI_PH; ++j)
                #pragma unroll
                for (int ni = 0; ni < 4; ++ni)
                    #pragma unroll
                    for (int kk = 0; kk < 2; ++kk)
                        acc[MI_PH * p + j][ni] = __builtin_amdgcn_mfma_f32_16x16x32_bf16(
                            a[j][kk], bfr[ni][kk], acc[MI_PH * p + j][ni], 0, 0, 0);
            __builtin_amdgcn_s_setprio(0);
            if (p == 3) { if (pf) { VMC6(); } else { VMC0(); } }
            SBAR();
        }
    }

    // -------- epilogue: ReLU + store --------
    const int orow0 = bm * BM + wm * (BM / 2) + fq * 4;
    const int ocol0 = bn * 256 + wn * 64 + fr;
    #pragma unroll
    for (int mi = 0; mi < M_REP; ++mi)
        #pragma unroll
        for (int ni = 0; ni < 4; ++ni)
            #pragma unroll
            for (int r = 0; r < 4; ++r) {
                float v = fmaxf(acc[mi][ni][r], 0.f);
                size_t off = (size_t)(orow0 + mi * 16 + r) * DD + (ocol0 + ni * 16);
                if (A_FP32) ((unsigned short*)Cp)[off] = f2bf(v);
                else        ((float*)Cp)[off] = v;
            }
}

// ---------------- fallback (tiny workspace): fused fp32 VALU path
__global__ __launch_bounds__(256) void fallback_fused(
        const float* __restrict__ x,
        const float* __restrict__ th1, const float* __restrict__ sg1,
        const float* __restrict__ th2, const float* __restrict__ sg2,
        float* __restrict__ out) {
    __shared__ float xr[8][DD];
    __shared__ float y1[8][DD];
    const int rb = blockIdx.x * 8;
    const int t = threadIdx.x;
    for (int r = 0; r < 8; ++r)
        for (int i = t; i < DD; i += 256)
            xr[r][i] = x[(size_t)(rb + r) * DD + i];
    __syncthreads();
    for (int jo = 0; jo < 4; ++jo) {
        const int j = jo * 256 + t;
        float a[8] = {0, 0, 0, 0, 0, 0, 0, 0};
        for (int k = 0; k < DD; ++k) {
            float tv = th1[(size_t)k * DD + j];
            float w = tv > 0.f ? tv * sg1[(size_t)k * DD + j] : 0.f;
            #pragma unroll
            for (int r = 0; r < 8; ++r) a[r] += xr[r][k] * w;
        }
        #pragma unroll
        for (int r = 0; r < 8; ++r) y1[r][j] = fmaxf(a[r], 0.f);
    }
    __syncthreads();
    for (int jo = 0; jo < 4; ++jo) {
        const int j = jo * 256 + t;
        float a[8] = {0, 0, 0, 0, 0, 0, 0, 0};
        for (int k = 0; k < DD; ++k) {
            float tv = th2[(size_t)k * DD + j];
            float w = tv > 0.f ? tv * sg2[(size_t)k * DD + j] : 0.f;
            #pragma unroll
            for (int r = 0; r < 8; ++r) a[r] += y1[r][k] * w;
        }
        #pragma unroll
        for (int r = 0; r < 8; ++r) out[(size_t)(rb + r) * DD + j] = fmaxf(a[r], 0.f);
    }
}

extern "C" void kernel_launch(void* const* d_in, const int* in_sizes, int n_in,
                              void* d_out, int out_size, void* d_ws, size_t ws_size,
                              hipStream_t stream) {
    const float* x   = (const float*)d_in[0];
    const float* th1 = (const float*)d_in[1];
    const float* sg1 = (const float*)d_in[2];
    const float* th2 = (const float*)d_in[3];
    const float* sg2 = (const float*)d_in[4];
    float* out = (float*)d_out;

    const size_t need = ((size_t)2 * 1024 * 1024 + (size_t)MROWS * 1024) * 2;
    if (ws_size >= need) {
        unsigned short* wT1 = (unsigned short*)d_ws;
        unsigned short* wT2 = wT1 + 1024 * 1024;
        unsigned short* Y1  = wT2 + 1024 * 1024;
        build_wT_kernel<<<dim3(16, 16, 2), 256, 0, stream>>>(th1, sg1, th2, sg2, wT1, wT2);
        gemm8p<true ><<<dim3((MROWS / 128) * 4), 512, 0, stream>>>(x,  wT1, Y1);
        gemm8p<false><<<dim3((MROWS / 256) * 4), 512, 0, stream>>>(Y1, wT2, out);
    } else {
        fallback_fused<<<MROWS / 8, 256, 0, stream>>>(x, th1, sg1, th2, sg2, out);
    }
}

// Round 3
// 204.845 us; speedup vs baseline: 1.3331x; 1.2617x over previous
//
#include <hip/hip_runtime.h>
#include <stdint.h>

#define DD 1024
#define MROWS 32768
#define NT 16   // K-tiles: 1024 / 64

typedef __attribute__((ext_vector_type(8))) short short8;
typedef __attribute__((ext_vector_type(8))) unsigned short ushort8;
typedef __attribute__((ext_vector_type(4))) float f32x4;

static __device__ __forceinline__ unsigned short f2bf(float f) {
    union { float f; uint32_t u; } c;
    c.f = f;
    uint32_t u = c.u;
    u += 0x7FFFu + ((u >> 16) & 1u);   // RNE
    return (unsigned short)(u >> 16);
}

static __device__ __forceinline__ void gload_lds16(const void* g, void* l) {
    __builtin_amdgcn_global_load_lds(
        (const __attribute__((address_space(1))) uint32_t*)g,
        (__attribute__((address_space(3))) uint32_t*)l,
        16, 0, 0);
}

#define SBAR() __builtin_amdgcn_s_barrier()

// ---------------- weight reconstruction: wT[n][k] = bf16(th*sign*(th>0))[k][n]
__global__ __launch_bounds__(256) void build_wT_kernel(
        const float* __restrict__ th1, const float* __restrict__ sg1,
        const float* __restrict__ th2, const float* __restrict__ sg2,
        unsigned short* __restrict__ wT1, unsigned short* __restrict__ wT2) {
    __shared__ unsigned short tile[64][65];
    const float* th = blockIdx.z ? th2 : th1;
    const float* sg = blockIdx.z ? sg2 : sg1;
    unsigned short* wT = blockIdx.z ? wT2 : wT1;
    const int bk = blockIdx.x, bn = blockIdx.y, t = threadIdx.x;
    #pragma unroll
    for (int i = 0; i < 4; ++i) {
        int idx = i * 256 + t;
        int r = idx >> 4, cg = idx & 15;
        size_t base = (size_t)(bk * 64 + r) * DD + bn * 64 + cg * 4;
        const float4 tv = *(const float4*)&th[base];
        const float4 sv = *(const float4*)&sg[base];
        tile[r][cg * 4 + 0] = f2bf(tv.x > 0.f ? tv.x * sv.x : 0.f);
        tile[r][cg * 4 + 1] = f2bf(tv.y > 0.f ? tv.y * sv.y : 0.f);
        tile[r][cg * 4 + 2] = f2bf(tv.z > 0.f ? tv.z * sv.z : 0.f);
        tile[r][cg * 4 + 3] = f2bf(tv.w > 0.f ? tv.w * sv.w : 0.f);
    }
    __syncthreads();
    #pragma unroll
    for (int i = 0; i < 4; ++i) {
        int idx = i * 256 + t;
        int nr = idx >> 4, kg = idx & 15;
        uint32_t lo = tile[kg * 4 + 0][nr] | ((uint32_t)tile[kg * 4 + 1][nr] << 16);
        uint32_t hi = tile[kg * 4 + 2][nr] | ((uint32_t)tile[kg * 4 + 3][nr] << 16);
        *(uint2*)&wT[(size_t)(bn * 64 + nr) * DD + bk * 64 + kg * 4] = make_uint2(lo, hi);
    }
}

// One phase: 4 A-frag ds_reads (+8 B-frag reads if LOADB), stage issue,
// barrier, setprio-wrapped 16 MFMA. Caller adds trailing (vmcnt+)barrier.
template<int Q, bool LOADB, typename F>
static __device__ __forceinline__ void phase_t(
        const unsigned short* sAp, const unsigned short* sBp,
        int wm, int wn, int fr, int fq,
        f32x4 (&acc)[8][4], short8 (&bfr)[4][2], F&& stage) {
    short8 a0[2][2];
    #pragma unroll
    for (int j = 0; j < 2; ++j)
        #pragma unroll
        for (int kk = 0; kk < 2; ++kk) {
            int row = Q * 64 + wm * 32 + j * 16 + fr;
            int off = (kk * 64 + fq * 16) ^ ((row & 7) << 4);
            a0[j][kk] = *(const short8*)((const char*)sAp + row * 128 + off);
        }
    if (LOADB) {
        #pragma unroll
        for (int ni = 0; ni < 4; ++ni)
            #pragma unroll
            for (int kk = 0; kk < 2; ++kk) {
                int row = wn * 64 + ni * 16 + fr;
                int off = (kk * 64 + fq * 16) ^ ((row & 7) << 4);
                bfr[ni][kk] = *(const short8*)((const char*)sBp + row * 128 + off);
            }
    }
    stage();
    SBAR();
    __builtin_amdgcn_s_setprio(1);
    #pragma unroll
    for (int j = 0; j < 2; ++j)
        #pragma unroll
        for (int ni = 0; ni < 4; ++ni)
            #pragma unroll
            for (int kk = 0; kk < 2; ++kk)
                acc[Q * 2 + j][ni] = __builtin_amdgcn_mfma_f32_16x16x32_bf16(
                    a0[j][kk], bfr[ni][kk], acc[Q * 2 + j][ni], 0, 0, 0);
    __builtin_amdgcn_s_setprio(0);
}

// ---------------- static 8-phase / 2-K-tile GEMM: C = relu(A . Bt^T)
// A_FP32=true : A fp32 (x), reg-staged with fp32->bf16 cvt, stores bf16 (Y1)
// A_FP32=false: A bf16 (Y1) via global_load_lds, stores fp32 (out)
template<bool A_FP32>
__global__ __launch_bounds__(512, 2) void gemm8p(
        const void* __restrict__ Ap,
        const unsigned short* __restrict__ Bt,   // [1024 n][1024 k] bf16
        void* __restrict__ Cp) {
    __shared__ unsigned short sA0[256 * 64];
    __shared__ unsigned short sA1[256 * 64];
    __shared__ unsigned short sB0[256 * 64];
    __shared__ unsigned short sB1[256 * 64];

    const int tid = threadIdx.x;
    const int lane = tid & 63, wid = tid >> 6;
    const int wm = wid >> 2, wn = wid & 3;
    const int fr = lane & 15, fq = lane >> 4;

    // T1: XCD-chunked swizzle, bn-minor (A-panel-sharing blocks co-XCD)
    const int s = blockIdx.x;
    const int L = (s & 7) * 64 + (s >> 3);     // 512 blocks, bijective
    const int bm = L >> 2, bn = L & 3;

    const unsigned short* srcB = Bt + (size_t)(bn * 256) * DD;
    const unsigned short* srcA = nullptr;
    const float* af = nullptr;
    if constexpr (A_FP32) af = (const float*)Ap + (size_t)(bm * 256) * DD;
    else srcA = (const unsigned short*)Ap + (size_t)(bm * 256) * DD;

    // global_load_lds: linear LDS dest (wave-uniform base + lane*16B),
    // pre-swizzled global source slot (involution slot^ (row&7)).
    auto stG = [&](unsigned short* dst, const unsigned short* src, int half, int kt) {
        #pragma unroll
        for (int j = 0; j < 2; ++j) {
            int r0 = half * 128 + j * 64 + wid * 8;
            int r = r0 + (lane >> 3);
            gload_lds16(src + (size_t)r * DD + kt * 64 + ((lane & 7) ^ ((lane >> 3) & 7)) * 8,
                        dst + r0 * 64);
        }
    };

    // gemm1 A staging: 16 fp32 per thread -> 16 bf16 -> 2 swizzled b128 writes
    f32x4 P0[4], P1[4];
    auto ldA = [&](f32x4 R[4], int tile, int half) {
        const float* p = af + (size_t)(half * 128 + (tid >> 2)) * DD + tile * 64 + (tid & 3) * 16;
        #pragma unroll
        for (int i = 0; i < 4; ++i) R[i] = *(const f32x4*)(p + 4 * i);
    };
    auto wrA = [&](unsigned short* sAp, int half, f32x4 R[4]) {
        int r = half * 128 + (tid >> 2);
        int s0 = (tid & 3) * 2;
        ushort8 w0, w1;
        #pragma unroll
        for (int i = 0; i < 4; ++i) {
            w0[i] = f2bf(R[0][i]); w0[4 + i] = f2bf(R[1][i]);
            w1[i] = f2bf(R[2][i]); w1[4 + i] = f2bf(R[3][i]);
        }
        *(ushort8*)((char*)sAp + r * 128 + (((s0    ) ^ (r & 7)) << 4)) = w0;
        *(ushort8*)((char*)sAp + r * 128 + (((s0 + 1) ^ (r & 7)) << 4)) = w1;
    };

    const f32x4 vz = {0.f, 0.f, 0.f, 0.f};
    f32x4 acc[8][4];
    #pragma unroll
    for (int i = 0; i < 8; ++i)
        #pragma unroll
        for (int j = 0; j < 4; ++j) acc[i][j] = vz;
    short8 bfr[4][2];

    // -------- prologue: B(t0),B(t1) (+A(t0) staged; A(t1) held in regs) ----
    if constexpr (A_FP32) {
        stG(sB0, srcB, 0, 0); stG(sB0, srcB, 1, 0);
        stG(sB1, srcB, 0, 1); stG(sB1, srcB, 1, 1);
        ldA(P0, 0, 0); ldA(P1, 0, 1);
        wrA(sA0, 0, P0); wrA(sA0, 1, P1);
        ldA(P0, 1, 0); ldA(P1, 1, 1);   // tile1 halves held; written at ph1
    } else {
        stG(sB0, srcB, 0, 0); stG(sB0, srcB, 1, 0);
        stG(sA0, srcA, 0, 0); stG(sA0, srcA, 1, 0);
        stG(sB1, srcB, 0, 1); stG(sB1, srcB, 1, 1);
    }
    __syncthreads();   // one-time full drain (prologue only)

    #pragma unroll 1
    for (int kt2 = 0; kt2 < NT; kt2 += 2) {
        const bool sN = (kt2 + 2 < NT);   // stage tiles kt2+2 / kt2+3 (equiv for even NT)

        // ph1 (t0 q0): stage sA1 both halves <- tile kt2+1
        phase_t<0, true>(sA0, sB0, wm, wn, fr, fq, acc, bfr, [&] {
            if constexpr (A_FP32) {
                wrA(sA1, 0, P0); wrA(sA1, 1, P1);
                if (sN) { ldA(P0, kt2 + 2, 0); ldA(P1, kt2 + 2, 1); }
            } else {
                stG(sA1, srcA, 0, kt2 + 1); stG(sA1, srcA, 1, kt2 + 1);
            }
        });
        SBAR();
        // ph2 (t0 q1): stage sB0.lo <- kt2+2
        phase_t<1, false>(sA0, sB0, wm, wn, fr, fq, acc, bfr, [&] {
            if (sN) stG(sB0, srcB, 0, kt2 + 2);
        });
        SBAR();
        // ph3 (t0 q2): stage sB0.hi
        phase_t<2, false>(sA0, sB0, wm, wn, fr, fq, acc, bfr, [&] {
            if (sN) stG(sB0, srcB, 1, kt2 + 2);
        });
        SBAR();
        // ph4 (t0 q3): counted vmcnt (never 0)
        phase_t<3, false>(sA0, sB0, wm, wn, fr, fq, acc, bfr, [&] {});
        if constexpr (A_FP32) asm volatile("s_waitcnt vmcnt(12)" ::: "memory");
        else                  asm volatile("s_waitcnt vmcnt(4)" ::: "memory");
        SBAR();
        // ph5 (t1 q0): stage sA0.lo <- kt2+2
        phase_t<0, true>(sA1, sB1, wm, wn, fr, fq, acc, bfr, [&] {
            if constexpr (A_FP32) {
                if (sN) { wrA(sA0, 0, P0); ldA(P0, kt2 + 3, 0); }
            } else {
                if (sN) stG(sA0, srcA, 0, kt2 + 2);
            }
        });
        SBAR();
        // ph6 (t1 q1): stage sA0.hi
        phase_t<1, false>(sA1, sB1, wm, wn, fr, fq, acc, bfr, [&] {
            if constexpr (A_FP32) {
                if (sN) { wrA(sA0, 1, P1); ldA(P1, kt2 + 3, 1); }
            } else {
                if (sN) stG(sA0, srcA, 1, kt2 + 2);
            }
        });
        SBAR();
        // ph7 (t1 q2): stage sB1.lo <- kt2+3
        phase_t<2, false>(sA1, sB1, wm, wn, fr, fq, acc, bfr, [&] {
            if (sN) stG(sB1, srcB, 0, kt2 + 3);
        });
        SBAR();
        // ph8 (t1 q3): stage sB1.hi; counted vmcnt
        phase_t<3, false>(sA1, sB1, wm, wn, fr, fq, acc, bfr, [&] {
            if (sN) stG(sB1, srcB, 1, kt2 + 3);
        });
        if constexpr (A_FP32) asm volatile("s_waitcnt vmcnt(12)" ::: "memory");
        else                  asm volatile("s_waitcnt vmcnt(4)" ::: "memory");
        SBAR();
    }

    // -------- epilogue: ReLU + store --------
    #pragma unroll
    for (int i = 0; i < 8; ++i)
        #pragma unroll
        for (int ni = 0; ni < 4; ++ni)
            #pragma unroll
            for (int r = 0; r < 4; ++r) {
                float v = fmaxf(acc[i][ni][r], 0.f);
                int row = bm * 256 + (i >> 1) * 64 + wm * 32 + (i & 1) * 16 + fq * 4 + r;
                int col = bn * 256 + wn * 64 + ni * 16 + fr;
                size_t off = (size_t)row * DD + col;
                if (A_FP32) ((unsigned short*)Cp)[off] = f2bf(v);
                else        ((float*)Cp)[off] = v;
            }
}

// ---------------- fallback (tiny workspace): fused fp32 VALU path
__global__ __launch_bounds__(256) void fallback_fused(
        const float* __restrict__ x,
        const float* __restrict__ th1, const float* __restrict__ sg1,
        const float* __restrict__ th2, const float* __restrict__ sg2,
        float* __restrict__ out) {
    __shared__ float xr[8][DD];
    __shared__ float y1[8][DD];
    const int rb = blockIdx.x * 8;
    const int t = threadIdx.x;
    for (int r = 0; r < 8; ++r)
        for (int i = t; i < DD; i += 256)
            xr[r][i] = x[(size_t)(rb + r) * DD + i];
    __syncthreads();
    for (int jo = 0; jo < 4; ++jo) {
        const int j = jo * 256 + t;
        float a[8] = {0, 0, 0, 0, 0, 0, 0, 0};
        for (int k = 0; k < DD; ++k) {
            float tv = th1[(size_t)k * DD + j];
            float w = tv > 0.f ? tv * sg1[(size_t)k * DD + j] : 0.f;
            #pragma unroll
            for (int r = 0; r < 8; ++r) a[r] += xr[r][k] * w;
        }
        #pragma unroll
        for (int r = 0; r < 8; ++r) y1[r][j] = fmaxf(a[r], 0.f);
    }
    __syncthreads();
    for (int jo = 0; jo < 4; ++jo) {
        const int j = jo * 256 + t;
        float a[8] = {0, 0, 0, 0, 0, 0, 0, 0};
        for (int k = 0; k < DD; ++k) {
            float tv = th2[(size_t)k * DD + j];
            float w = tv > 0.f ? tv * sg2[(size_t)k * DD + j] : 0.f;
            #pragma unroll
            for (int r = 0; r < 8; ++r) a[r] += y1[r][k] * w;
        }
        #pragma unroll
        for (int r = 0; r < 8; ++r) out[(size_t)(rb + r) * DD + j] = fmaxf(a[r], 0.f);
    }
}

extern "C" void kernel_launch(void* const* d_in, const int* in_sizes, int n_in,
                              void* d_out, int out_size, void* d_ws, size_t ws_size,
                              hipStream_t stream) {
    const float* x   = (const float*)d_in[0];
    const float* th1 = (const float*)d_in[1];
    const float* sg1 = (const float*)d_in[2];
    const float* th2 = (const float*)d_in[3];
    const float* sg2 = (const float*)d_in[4];
    float* out = (float*)d_out;

    const size_t need = ((size_t)2 * 1024 * 1024 + (size_t)MROWS * 1024) * 2;
    if (ws_size >= need) {
        unsigned short* wT1 = (unsigned short*)d_ws;
        unsigned short* wT2 = wT1 + 1024 * 1024;
        unsigned short* Y1  = wT2 + 1024 * 1024;
        build_wT_kernel<<<dim3(16, 16, 2), 256, 0, stream>>>(th1, sg1, th2, sg2, wT1, wT2);
        gemm8p<true ><<<dim3(512), 512, 0, stream>>>(x,  wT1, Y1);
        gemm8p<false><<<dim3(512), 512, 0, stream>>>(Y1, wT2, out);
    } else {
        fallback_fused<<<MROWS / 8, 256, 0, stream>>>(x, th1, sg1, th2, sg2, out);
    }
}